// Round 6
// baseline (244.130 us; speedup 1.0000x reference)
//
#include <hip/hip_runtime.h>
#include <math.h>

#define NB 8
#define NN 2048
#define IN_DIM 256
#define OUT_DIM 64
#define ALPHA 0.2f
#define JSPLIT 8

typedef __attribute__((ext_vector_type(8))) short bf16x8;
typedef __attribute__((ext_vector_type(4))) float f32x4;
typedef __attribute__((ext_vector_type(4))) int   i32x4;   // clang vector: OK for nontemporal builtins

// float -> bf16 (RNE), bit trick (no NaN inputs here)
__device__ __forceinline__ unsigned short f2bf(float x) {
    union { float f; unsigned u; } v; v.f = x;
    unsigned r = v.u + 0x7FFF + ((v.u >> 16) & 1);
    return (unsigned short)(r >> 16);
}
__device__ __forceinline__ float bf2f(unsigned short b) {
    union { unsigned u; float f; } v; v.u = ((unsigned)b) << 16;
    return v.f;
}

// ---------------------------------------------------------------------------
// Kernel 1 (unchanged from R4): Wh = h@W via bf16 MFMA -> Whbt [b][d][j] bf16,
// s1 = Wh@a1, s2 = Wh@a2.  Grid 256 x 256thr; wave = 16-row i-tile.
// ---------------------------------------------------------------------------
#define WT_STRIDE 264
__global__ __launch_bounds__(256) void wh_kernel(const float* __restrict__ h,
                                                 const float* __restrict__ W,
                                                 const float* __restrict__ a,
                                                 unsigned short* __restrict__ Whbt,
                                                 float* __restrict__ s1,
                                                 float* __restrict__ s2) {
    __shared__ unsigned short Wt[OUT_DIM * WT_STRIDE];
    const int t = threadIdx.x;

    #pragma unroll 8
    for (int rep = 0; rep < 64; ++rep) {
        const int id = rep * 256 + t;
        const int k = id >> 6, n = id & 63;
        Wt[n * WT_STRIDE + k] = f2bf(W[id]);
    }
    __syncthreads();

    const int lane = t & 63, wv = t >> 6;
    const int m = lane & 15, quad = lane >> 4;
    const long gr0 = (long)(blockIdx.x * 4 + wv) * 16;

    f32x4 acc[4];
    #pragma unroll
    for (int nt = 0; nt < 4; ++nt) acc[nt] = (f32x4){0.f, 0.f, 0.f, 0.f};

    #pragma unroll
    for (int ks = 0; ks < 8; ++ks) {
        const int k0 = ks * 32;
        const float* hp = h + (gr0 + m) * IN_DIM + k0 + quad * 8;
        const float4 ha = *(const float4*)hp;
        const float4 hb = *(const float4*)(hp + 4);
        bf16x8 af;
        af[0] = (short)f2bf(ha.x); af[1] = (short)f2bf(ha.y);
        af[2] = (short)f2bf(ha.z); af[3] = (short)f2bf(ha.w);
        af[4] = (short)f2bf(hb.x); af[5] = (short)f2bf(hb.y);
        af[6] = (short)f2bf(hb.z); af[7] = (short)f2bf(hb.w);
        #pragma unroll
        for (int nt = 0; nt < 4; ++nt) {
            const bf16x8 bf_ = *(const bf16x8*)(const void*)
                &Wt[(nt * 16 + m) * WT_STRIDE + k0 + quad * 8];
            acc[nt] = __builtin_amdgcn_mfma_f32_16x16x32_bf16(af, bf_, acc[nt], 0, 0, 0);
        }
    }

    const int b  = (int)(gr0 >> 11);
    const int ib = (int)(gr0 & 2047);

    #pragma unroll
    for (int nt = 0; nt < 4; ++nt) {
        ushort4 w4;
        w4.x = f2bf(acc[nt][0]); w4.y = f2bf(acc[nt][1]);
        w4.z = f2bf(acc[nt][2]); w4.w = f2bf(acc[nt][3]);
        *(ushort4*)&Whbt[((long)(b * OUT_DIM + nt * 16 + m) << 11) + ib + quad * 4] = w4;
    }

    float a1v[4], a2v[4];
    #pragma unroll
    for (int nt = 0; nt < 4; ++nt) {
        a1v[nt] = a[nt * 16 + m];
        a2v[nt] = a[OUT_DIM + nt * 16 + m];
    }
    #pragma unroll
    for (int reg = 0; reg < 4; ++reg) {
        float p1 = 0.f, p2 = 0.f;
        #pragma unroll
        for (int nt = 0; nt < 4; ++nt) {
            p1 += acc[nt][reg] * a1v[nt];
            p2 += acc[nt][reg] * a2v[nt];
        }
        #pragma unroll
        for (int off = 1; off < 16; off <<= 1) {
            p1 += __shfl_xor(p1, off, 64);
            p2 += __shfl_xor(p2, off, 64);
        }
        if (m == 0) {
            s1[gr0 + quad * 4 + reg] = p1;
            s2[gr0 + quad * 4 + reg] = p2;
        }
    }
}

// ---------------------------------------------------------------------------
// Kernel 2: masked softmax + P@Wh via bf16 MFMA, ZERO LDS / ZERO barriers.
// P computed directly in MFMA A-fragment layout: lane (m,quad) owns row i0+m,
// k-slice quad*8..+7.  Per 32-j step: 2x i32x4 adj loads (16 rows x 128B
// segments, coalesced) + 2x float4 s2 + 8 exp -> bf16x8 A-frag in registers,
// 4x 16B Whbt B-frags (L2-hot), 4x mfma.  adj/s2 rotated one step ahead.
// Row sums: quads share a row -> epilogue shfl_xor(16,32).
// Grid NB*(NN/64)*JSPLIT = 2048 blocks x 4 waves.
// ---------------------------------------------------------------------------
__device__ __forceinline__ float pcalc(int av, float s2e, float s1v) {
    float e = s1v + s2e;
    e = e > 0.f ? e : ALPHA * e;
    const float p = __expf(e);
    return av != 0 ? p : 0.f;
}

__global__ __launch_bounds__(256) void attn_kernel(const int* __restrict__ adj,
                                                   const unsigned short* __restrict__ Whbt,
                                                   const float* __restrict__ s1,
                                                   const float* __restrict__ s2,
                                                   float* __restrict__ part,
                                                   float* __restrict__ lpart) {
    const int t = threadIdx.x, lane = t & 63, wv = t >> 6;
    const int bid = blockIdx.x;
    const int js  = bid & (JSPLIT - 1);
    const int itg = (bid >> 3) & 31;
    const int b   = bid >> 8;
    const int i0  = itg * 64 + wv * 16;
    const int jlo = js * (NN / JSPLIT);        // 256-wide j slice

    const int m = lane & 15, quad = lane >> 4;

    const int*   adjp = adj + (long)b * NN * NN + (long)(i0 + m) * NN + jlo + quad * 8;
    const float* s2p  = s2 + b * NN + jlo + quad * 8;
    const unsigned short* wbase = Whbt + ((long)(b * OUT_DIM) << 11) + jlo + quad * 8;
    const float s1v = s1[b * NN + i0 + m];

    f32x4 acc[4];
    #pragma unroll
    for (int nt = 0; nt < 4; ++nt) acc[nt] = (f32x4){0.f, 0.f, 0.f, 0.f};
    float lsum = 0.f;

    // rotate-prefetch step 0
    i32x4  av0 = __builtin_nontemporal_load((const i32x4*)adjp);
    i32x4  av1 = __builtin_nontemporal_load((const i32x4*)(adjp + 4));
    float4 sv0 = *(const float4*)s2p;
    float4 sv1 = *(const float4*)(s2p + 4);

    #pragma unroll
    for (int ks = 0; ks < NN / JSPLIT / 32; ++ks) {   // 8 steps
        const int j0 = ks * 32;

        // B-frags (L2-hot); consumed ~200 cyc later by MFMA
        bf16x8 bfr[4];
        #pragma unroll
        for (int nt = 0; nt < 4; ++nt)
            bfr[nt] = *(const bf16x8*)(const void*)
                &wbase[(((long)(nt * 16 + m)) << 11) + j0];

        const i32x4  ca0 = av0, ca1 = av1;
        const float4 cs0 = sv0, cs1 = sv1;
        if (ks < NN / JSPLIT / 32 - 1) {               // prefetch next step
            av0 = __builtin_nontemporal_load((const i32x4*)(adjp + j0 + 32));
            av1 = __builtin_nontemporal_load((const i32x4*)(adjp + j0 + 36));
            sv0 = *(const float4*)(s2p + j0 + 32);
            sv1 = *(const float4*)(s2p + j0 + 36);
        }

        float pv[8];
        pv[0] = pcalc(ca0.x, cs0.x, s1v); pv[1] = pcalc(ca0.y, cs0.y, s1v);
        pv[2] = pcalc(ca0.z, cs0.z, s1v); pv[3] = pcalc(ca0.w, cs0.w, s1v);
        pv[4] = pcalc(ca1.x, cs1.x, s1v); pv[5] = pcalc(ca1.y, cs1.y, s1v);
        pv[6] = pcalc(ca1.z, cs1.z, s1v); pv[7] = pcalc(ca1.w, cs1.w, s1v);

        bf16x8 af;
        #pragma unroll
        for (int e = 0; e < 8; ++e) {
            const unsigned short bb = f2bf(pv[e]);
            af[e] = (short)bb;
            lsum += bf2f(bb);          // sum the ROUNDED p: num/denom consistent
        }

        #pragma unroll
        for (int nt = 0; nt < 4; ++nt)
            acc[nt] = __builtin_amdgcn_mfma_f32_16x16x32_bf16(af, bfr[nt], acc[nt], 0, 0, 0);
    }

    // ---- l partial: 4 quads share row i0+m ----
    lsum += __shfl_xor(lsum, 16, 64);
    lsum += __shfl_xor(lsum, 32, 64);
    if (quad == 0)
        lpart[js * (NB * NN) + b * NN + i0 + m] = lsum;

    // ---- out partials.  C layout: i = i0+quad*4+reg, d = nt*16+m ----
    float* pp = part + (long)js * ((long)NB * NN * OUT_DIM)
                     + ((long)(b * NN + i0) << 6);
    #pragma unroll
    for (int nt = 0; nt < 4; ++nt)
        #pragma unroll
        for (int reg = 0; reg < 4; ++reg)
            pp[(quad * 4 + reg) * OUT_DIM + nt * 16 + m] = acc[nt][reg];
}

// ---------------------------------------------------------------------------
// Kernel 3: out = (sum_js part) / (sum_js lpart), float4 coalesced.
// ---------------------------------------------------------------------------
__global__ __launch_bounds__(256) void finalize_kernel(const float* __restrict__ part,
                                                       const float* __restrict__ lpart,
                                                       float* __restrict__ out) {
    const int idx = blockIdx.x * 256 + threadIdx.x;
    const int row = idx >> 4;
    float l = 0.f;
    #pragma unroll
    for (int s = 0; s < JSPLIT; ++s) l += lpart[s * (NB * NN) + row];
    float4 v = make_float4(0.f, 0.f, 0.f, 0.f);
    const float4* p4 = (const float4*)part;
    #pragma unroll
    for (int s = 0; s < JSPLIT; ++s) {
        const float4 p = p4[(long)s * ((long)NB * NN * OUT_DIM / 4) + idx];
        v.x += p.x; v.y += p.y; v.z += p.z; v.w += p.w;
    }
    const float inv = 1.f / l;
    v.x *= inv; v.y *= inv; v.z *= inv; v.w *= inv;
    ((float4*)out)[idx] = v;
}

// ---------------------------------------------------------------------------
extern "C" void kernel_launch(void* const* d_in, const int* in_sizes, int n_in,
                              void* d_out, int out_size, void* d_ws, size_t ws_size,
                              hipStream_t stream) {
    const float* h   = (const float*)d_in[0];
    const int*   adj = (const int*)d_in[1];
    const float* W   = (const float*)d_in[2];
    const float* a   = (const float*)d_in[3];
    float* out = (float*)d_out;

    float* s1    = (float*)d_ws;                          // 16K f32
    float* s2    = s1 + NB * NN;                          // 16K f32
    float* lpart = s2 + NB * NN;                          // 128K f32
    float* part  = lpart + JSPLIT * NB * NN;              // 8M f32 = 32 MB
    unsigned short* Whbt =
        (unsigned short*)(part + (long)JSPLIT * NB * NN * OUT_DIM);  // 1M bf16

    wh_kernel<<<NB * NN / 64, 256, 0, stream>>>(h, W, a, Whbt, s1, s2);
    attn_kernel<<<NB * (NN / 64) * JSPLIT, 256, 0, stream>>>(adj, Whbt, s1, s2, part, lpart);
    finalize_kernel<<<NB * NN * OUT_DIM / 4 / 256, 256, 0, stream>>>(part, lpart, out);
}

// Round 7
// 235.724 us; speedup vs baseline: 1.0357x; 1.0357x over previous
//
#include <hip/hip_runtime.h>
#include <math.h>

#define NB 8
#define NN 2048
#define IN_DIM 256
#define OUT_DIM 64
#define ALPHA 0.2f
#define JSPLIT 4

typedef __attribute__((ext_vector_type(8))) short bf16x8;
typedef __attribute__((ext_vector_type(4))) float f32x4;
typedef __attribute__((ext_vector_type(4))) int   i32x4;

// float -> bf16 (RNE), bit trick (no NaN inputs here)
__device__ __forceinline__ unsigned short f2bf(float x) {
    union { float f; unsigned u; } v; v.f = x;
    unsigned r = v.u + 0x7FFF + ((v.u >> 16) & 1);
    return (unsigned short)(r >> 16);
}

// ---------------------------------------------------------------------------
// Kernel 1 (unchanged): Wh = h@W via bf16 MFMA -> Whbt [b][d][j] bf16,
// s1 = Wh@a1, s2 = Wh@a2.  Grid 256 x 256thr; wave = 16-row i-tile.
// ---------------------------------------------------------------------------
#define WT_STRIDE 264
__global__ __launch_bounds__(256) void wh_kernel(const float* __restrict__ h,
                                                 const float* __restrict__ W,
                                                 const float* __restrict__ a,
                                                 unsigned short* __restrict__ Whbt,
                                                 float* __restrict__ s1,
                                                 float* __restrict__ s2) {
    __shared__ unsigned short Wt[OUT_DIM * WT_STRIDE];
    const int t = threadIdx.x;

    #pragma unroll 8
    for (int rep = 0; rep < 64; ++rep) {
        const int id = rep * 256 + t;
        const int k = id >> 6, n = id & 63;
        Wt[n * WT_STRIDE + k] = f2bf(W[id]);
    }
    __syncthreads();

    const int lane = t & 63, wv = t >> 6;
    const int m = lane & 15, quad = lane >> 4;
    const long gr0 = (long)(blockIdx.x * 4 + wv) * 16;

    f32x4 acc[4];
    #pragma unroll
    for (int nt = 0; nt < 4; ++nt) acc[nt] = (f32x4){0.f, 0.f, 0.f, 0.f};

    #pragma unroll
    for (int ks = 0; ks < 8; ++ks) {
        const int k0 = ks * 32;
        const float* hp = h + (gr0 + m) * IN_DIM + k0 + quad * 8;
        const float4 ha = *(const float4*)hp;
        const float4 hb = *(const float4*)(hp + 4);
        bf16x8 af;
        af[0] = (short)f2bf(ha.x); af[1] = (short)f2bf(ha.y);
        af[2] = (short)f2bf(ha.z); af[3] = (short)f2bf(ha.w);
        af[4] = (short)f2bf(hb.x); af[5] = (short)f2bf(hb.y);
        af[6] = (short)f2bf(hb.z); af[7] = (short)f2bf(hb.w);
        #pragma unroll
        for (int nt = 0; nt < 4; ++nt) {
            const bf16x8 bf_ = *(const bf16x8*)(const void*)
                &Wt[(nt * 16 + m) * WT_STRIDE + k0 + quad * 8];
            acc[nt] = __builtin_amdgcn_mfma_f32_16x16x32_bf16(af, bf_, acc[nt], 0, 0, 0);
        }
    }

    const int b  = (int)(gr0 >> 11);
    const int ib = (int)(gr0 & 2047);

    #pragma unroll
    for (int nt = 0; nt < 4; ++nt) {
        ushort4 w4;
        w4.x = f2bf(acc[nt][0]); w4.y = f2bf(acc[nt][1]);
        w4.z = f2bf(acc[nt][2]); w4.w = f2bf(acc[nt][3]);
        *(ushort4*)&Whbt[((long)(b * OUT_DIM + nt * 16 + m) << 11) + ib + quad * 4] = w4;
    }

    float a1v[4], a2v[4];
    #pragma unroll
    for (int nt = 0; nt < 4; ++nt) {
        a1v[nt] = a[nt * 16 + m];
        a2v[nt] = a[OUT_DIM + nt * 16 + m];
    }
    #pragma unroll
    for (int reg = 0; reg < 4; ++reg) {
        float p1 = 0.f, p2 = 0.f;
        #pragma unroll
        for (int nt = 0; nt < 4; ++nt) {
            p1 += acc[nt][reg] * a1v[nt];
            p2 += acc[nt][reg] * a2v[nt];
        }
        #pragma unroll
        for (int off = 1; off < 16; off <<= 1) {
            p1 += __shfl_xor(p1, off, 64);
            p2 += __shfl_xor(p2, off, 64);
        }
        if (m == 0) {
            s1[gr0 + quad * 4 + reg] = p1;
            s2[gr0 + quad * 4 + reg] = p2;
        }
    }
}

// ---------------------------------------------------------------------------
// Kernel 2: masked softmax + P@Wh via bf16 MFMA, zero LDS / zero barriers.
// JSPLIT=4: grid 1024, 16 steps of 32 j per wave.  PF=2 double-buffered
// adj/s2 prefetch (lookahead 2 x ~600cyc wall >= 900cyc HBM latency at
// 4 waves/SIMD, enforced by __launch_bounds__(256,4)).  Row sums via a 5th
// MFMA with B = 1.0 (bf16) — denominators accumulate in C-layout from the
// SAME rounded A-frag as the numerator; no shuffles, no per-step adds.
// ---------------------------------------------------------------------------
__device__ __forceinline__ float pcalc(int av, float s2e, float s1v) {
    float e = s1v + s2e;
    e = e > 0.f ? e : ALPHA * e;
    const float p = __expf(e);
    return av != 0 ? p : 0.f;
}

__global__ __launch_bounds__(256, 4) void attn_kernel(const int* __restrict__ adj,
                                                      const unsigned short* __restrict__ Whbt,
                                                      const float* __restrict__ s1,
                                                      const float* __restrict__ s2,
                                                      float* __restrict__ part,
                                                      float* __restrict__ lpart) {
    const int t = threadIdx.x, lane = t & 63, wv = t >> 6;
    const int bid = blockIdx.x;
    const int js  = bid & (JSPLIT - 1);
    const int itg = (bid >> 2) & 31;
    const int b   = bid >> 7;
    const int i0  = itg * 64 + wv * 16;
    const int jlo = js * (NN / JSPLIT);        // 512-wide j slice, 16 steps

    const int m = lane & 15, quad = lane >> 4;

    const int*   adjp = adj + (long)b * NN * NN + (long)(i0 + m) * NN + jlo + quad * 8;
    const float* s2p  = s2 + b * NN + jlo + quad * 8;
    const unsigned short* wbase = Whbt + ((long)(b * OUT_DIM) << 11) + jlo + quad * 8;
    const float s1v = s1[b * NN + i0 + m];

    f32x4 acc[4];
    #pragma unroll
    for (int nt = 0; nt < 4; ++nt) acc[nt] = (f32x4){0.f, 0.f, 0.f, 0.f};
    f32x4 racc = (f32x4){0.f, 0.f, 0.f, 0.f};

    bf16x8 bones;
    #pragma unroll
    for (int e = 0; e < 8; ++e) bones[e] = (short)0x3F80;   // 1.0 bf16

    // ---- software pipeline: 2 steps in flight (double-buffered) ----
    i32x4  av0[2], av1[2];
    float4 sv0[2], sv1[2];
    #pragma unroll
    for (int p = 0; p < 2; ++p) {
        av0[p] = __builtin_nontemporal_load((const i32x4*)(adjp + p * 32));
        av1[p] = __builtin_nontemporal_load((const i32x4*)(adjp + p * 32 + 4));
        sv0[p] = *(const float4*)(s2p + p * 32);
        sv1[p] = *(const float4*)(s2p + p * 32 + 4);
    }

    #pragma unroll 2
    for (int ks = 0; ks < 16; ++ks) {
        const int j0 = ks * 32;
        const int cur = ks & 1;

        // B-frags for this step (L2-hot; consumed after pcalc work)
        bf16x8 bfr[4];
        #pragma unroll
        for (int nt = 0; nt < 4; ++nt)
            bfr[nt] = *(const bf16x8*)(const void*)
                &wbase[(((long)(nt * 16 + m)) << 11) + j0];

        const i32x4  ca0 = av0[cur], ca1 = av1[cur];
        const float4 cs0 = sv0[cur], cs1 = sv1[cur];
        if (ks < 14) {                          // prefetch step ks+2 into cur
            av0[cur] = __builtin_nontemporal_load((const i32x4*)(adjp + j0 + 64));
            av1[cur] = __builtin_nontemporal_load((const i32x4*)(adjp + j0 + 68));
            sv0[cur] = *(const float4*)(s2p + j0 + 64);
            sv1[cur] = *(const float4*)(s2p + j0 + 68);
        }

        float pv[8];
        pv[0] = pcalc(ca0.x, cs0.x, s1v); pv[1] = pcalc(ca0.y, cs0.y, s1v);
        pv[2] = pcalc(ca0.z, cs0.z, s1v); pv[3] = pcalc(ca0.w, cs0.w, s1v);
        pv[4] = pcalc(ca1.x, cs1.x, s1v); pv[5] = pcalc(ca1.y, cs1.y, s1v);
        pv[6] = pcalc(ca1.z, cs1.z, s1v); pv[7] = pcalc(ca1.w, cs1.w, s1v);

        bf16x8 af;
        #pragma unroll
        for (int e = 0; e < 8; ++e) af[e] = (short)f2bf(pv[e]);

        #pragma unroll
        for (int nt = 0; nt < 4; ++nt)
            acc[nt] = __builtin_amdgcn_mfma_f32_16x16x32_bf16(af, bfr[nt], acc[nt], 0, 0, 0);
        racc = __builtin_amdgcn_mfma_f32_16x16x32_bf16(af, bones, racc, 0, 0, 0);
    }

    // ---- l partial: racc[reg] = rowsum(i0+quad*4+reg), replicated over m ----
    if (m == 0) {
        #pragma unroll
        for (int reg = 0; reg < 4; ++reg)
            lpart[js * (NB * NN) + b * NN + i0 + quad * 4 + reg] = racc[reg];
    }

    // ---- out partials.  C layout: i = i0+quad*4+reg, d = nt*16+m ----
    float* pp = part + (long)js * ((long)NB * NN * OUT_DIM)
                     + ((long)(b * NN + i0) << 6);
    #pragma unroll
    for (int nt = 0; nt < 4; ++nt)
        #pragma unroll
        for (int reg = 0; reg < 4; ++reg)
            pp[(quad * 4 + reg) * OUT_DIM + nt * 16 + m] = acc[nt][reg];
}

// ---------------------------------------------------------------------------
// Kernel 3: out = (sum_js part) / (sum_js lpart), float4 coalesced.
// ---------------------------------------------------------------------------
__global__ __launch_bounds__(256) void finalize_kernel(const float* __restrict__ part,
                                                       const float* __restrict__ lpart,
                                                       float* __restrict__ out) {
    const int idx = blockIdx.x * 256 + threadIdx.x;
    const int row = idx >> 4;
    float l = 0.f;
    #pragma unroll
    for (int s = 0; s < JSPLIT; ++s) l += lpart[s * (NB * NN) + row];
    float4 v = make_float4(0.f, 0.f, 0.f, 0.f);
    const float4* p4 = (const float4*)part;
    #pragma unroll
    for (int s = 0; s < JSPLIT; ++s) {
        const float4 p = p4[(long)s * ((long)NB * NN * OUT_DIM / 4) + idx];
        v.x += p.x; v.y += p.y; v.z += p.z; v.w += p.w;
    }
    const float inv = 1.f / l;
    v.x *= inv; v.y *= inv; v.z *= inv; v.w *= inv;
    ((float4*)out)[idx] = v;
}

// ---------------------------------------------------------------------------
extern "C" void kernel_launch(void* const* d_in, const int* in_sizes, int n_in,
                              void* d_out, int out_size, void* d_ws, size_t ws_size,
                              hipStream_t stream) {
    const float* h   = (const float*)d_in[0];
    const int*   adj = (const int*)d_in[1];
    const float* W   = (const float*)d_in[2];
    const float* a   = (const float*)d_in[3];
    float* out = (float*)d_out;

    float* s1    = (float*)d_ws;                          // 16K f32
    float* s2    = s1 + NB * NN;                          // 16K f32
    float* lpart = s2 + NB * NN;                          // 64K f32
    float* part  = lpart + JSPLIT * NB * NN;              // 4M f32 = 16 MB
    unsigned short* Whbt =
        (unsigned short*)(part + (long)JSPLIT * NB * NN * OUT_DIM);  // 1M bf16

    wh_kernel<<<NB * NN / 64, 256, 0, stream>>>(h, W, a, Whbt, s1, s2);
    attn_kernel<<<NB * (NN / 64) * JSPLIT, 256, 0, stream>>>(adj, Whbt, s1, s2, part, lpart);
    finalize_kernel<<<NB * NN * OUT_DIM / 4 / 256, 256, 0, stream>>>(part, lpart, out);
}